// Round 4
// baseline (146.482 us; speedup 1.0000x reference)
//
#include <hip/hip_runtime.h>
#include <math.h>

// ---- problem dims ----
#define BB 8
#define SS 512
#define NNODE 1024
#define NEDGE 2048
#define MAXN 4096
#define MAXE 8192
#define TYPED 16
#define MEMD 64
#define TENC 32
#define EEMB 128
#define OUTD 64
#define MSG 304      // 16+64+64+32+128
#define INGNN 192    // 128+64
#define EDIM 160     // 32+128
#define BN 8192      // B*N
#define BE 16384     // B*E

__device__ __forceinline__ float sigmoidf(float x){ return 1.f/(1.f + expf(-x)); }

// ---- init: zero accumulator span, first_pos=INT_MAX, and weight transposes (fused prepw) ----
__global__ void k_init(float* zero_base, int n_zero, int* first_pos,
                       const float* w_ih, const float* w_hh, const float* Wq,
                       const float* Wk, const float* Wv, const float* Wskip,
                       const float* We, const float* bq, const float* bk,
                       const float* bv, const float* bskip,
                       float* wihT, float* whhT, float* WcatT, float* WeT, float* bcat){
  int i = blockIdx.x*blockDim.x + threadIdx.x;
  int stride = gridDim.x*blockDim.x;
  for (int t=i; t<n_zero; t+=stride) zero_base[t] = 0.f;
  for (int t=i; t<MAXN; t+=stride) first_pos[t] = 0x7FFFFFFF;
  int j = i;
  const int n0 = 192*MSG;
  if (j < n0){ int r=j/MSG, c=j%MSG; wihT[c*192+r] = w_ih[j]; }
  else {
    j -= n0;
    if (j < 192*64){ int r=j/64, c=j%64; whhT[c*192+r] = w_hh[j]; }
    else {
      j -= 192*64;
      if (j < 4*64*192){
        int o = j/(64*192); int rem = j%(64*192); int q=rem/192, k=rem%192;
        const float* W = (o==0)?Wq:(o==1)?Wk:(o==2)?Wv:Wskip;
        WcatT[k*256 + o*64 + q] = W[rem];
      } else {
        j -= 4*64*192;
        if (j < 64*EDIM){ int q=j/EDIM, k=j%EDIM; WeT[k*64+q] = We[j]; }
        else {
          j -= 64*EDIM;
          if (j < 256){
            const float* b = (j<64)?bq:(j<128)?bk:(j<192)?bv:bskip;
            bcat[j] = b[j&63];
          }
        }
      }
    }
  }
}

// ---- messages for batch 0 + scatter-add into agg sums/counts ----
__global__ void k_msg(const int* ev_type, const int* src_ids, const float* src_mask,
                      const int* dst_ids, const float* dst_mask, const int* ev_edge,
                      const float* ev_emb, const float* ev_ts, const float* memory,
                      const float* last_update, const float* type_emb,
                      const float* time_w, const float* time_b,
                      float* agg_src, float* agg_dst, int* cnt_src, int* cnt_dst){
  int s = blockIdx.x;                 // event s of batch 0
  int et = ev_type[s];
  int sid = src_ids[s], did = dst_ids[s];
  float sm = src_mask[s], dm = dst_mask[s];
  float ts = ev_ts[s];
  float ns = (et >= 3) ? 1.f : 0.f;
  float ine = (et == 3 || et == 4) ? 1.f : 0.f;
  float rel = ts - last_update[ev_edge[s]] * dm;
  float tin = ts*ine + rel*dm;
  int d = threadIdx.x;
  if (d < MSG){
    float vs, vd;
    if (d < TYPED){ float t = type_emb[et*TYPED + d]; vs = t; vd = t; }
    else if (d < 80){ int c=d-16;  vs = memory[sid*MEMD+c]*sm; vd = memory[did*MEMD+c]*dm; }
    else if (d < 144){ int c=d-80; vs = memory[did*MEMD+c]*dm; vd = memory[sid*MEMD+c]*sm; }
    else if (d < 176){ int c=d-144; float ce = cosf(tin*time_w[c]+time_b[c])*ns; vs=ce; vd=ce; }
    else { float e = ev_emb[s*EEMB + (d-176)]; vs=e; vd=e; }
    atomicAdd(&agg_src[sid*MSG+d], vs*ns);
    atomicAdd(&agg_dst[did*MSG+d], vd*dm);
  }
  if (d == MSG){ atomicAdd(&cnt_src[sid], 1); atomicAdd(&cnt_dst[did], 1); }
}

// ---- first flat position of each node value + presence flags (fused) ----
__global__ void k_first(const int* node_ids, int* first_pos,
                        const int* src_ids, const int* dst_ids, int* ps, int* pd){
  int i = blockIdx.x*blockDim.x + threadIdx.x;
  if (i < BN) atomicMin(&first_pos[node_ids[i]], i);
  if (i < BB*SS){ ps[src_ids[i]] = 1; pd[dst_ids[i]] = 1; }
}

// ---- GRU memory update (one GRU per node; dst wins over src) ----
#define NT 4
__global__ __launch_bounds__(192) void k_gru(
    const float* agg_src, const float* agg_dst, const int* cnt_src, const int* cnt_dst,
    const int* ps, const int* pd, const float* memory,
    const float* wihT, const float* whhT, const float* b_ih, const float* b_hh,
    float* mem_new){
  __shared__ float xs[NT][MSG];
  __shared__ float hs[NT][MEMD];
  __shared__ float giL[NT][192];
  __shared__ float ghL[NT][192];
  __shared__ int mode[NT];
  int tid = threadIdx.x;
  int base = blockIdx.x * NT;
  if (tid < NT){
    int n = base + tid;
    mode[tid] = pd[n] ? 2 : (ps[n] ? 1 : 0);
  }
  __syncthreads();
  for (int idx = tid; idx < NT*MSG; idx += 192){
    int t = idx / MSG, d = idx % MSG;
    int n = base + t;
    float x = 0.f;
    int m = mode[t];
    if (m == 2){ int c = max(cnt_dst[n],1); x = agg_dst[n*MSG+d]/(float)c; }
    else if (m == 1){ int c = max(cnt_src[n],1); x = agg_src[n*MSG+d]/(float)c; }
    xs[t][d] = x;
  }
  for (int idx = tid; idx < NT*MEMD; idx += 192){
    int t = idx / MEMD, d = idx % MEMD;
    hs[t][d] = memory[(base+t)*MEMD + d];
  }
  __syncthreads();
  {
    float acc[NT];
    #pragma unroll
    for (int t=0;t<NT;t++) acc[t] = 0.f;
    #pragma unroll 4
    for (int k=0;k<MSG;k++){
      float w = wihT[k*192 + tid];
      #pragma unroll
      for (int t=0;t<NT;t++) acc[t] += w * xs[t][k];
    }
    float bi = b_ih[tid];
    #pragma unroll
    for (int t=0;t<NT;t++) giL[t][tid] = acc[t] + bi;
  }
  {
    float acc[NT];
    #pragma unroll
    for (int t=0;t<NT;t++) acc[t] = 0.f;
    #pragma unroll 4
    for (int k=0;k<MEMD;k++){
      float w = whhT[k*192 + tid];
      #pragma unroll
      for (int t=0;t<NT;t++) acc[t] += w * hs[t][k];
    }
    float bh = b_hh[tid];
    #pragma unroll
    for (int t=0;t<NT;t++) ghL[t][tid] = acc[t] + bh;
  }
  __syncthreads();
  if (tid < MEMD){
    #pragma unroll
    for (int t=0;t<NT;t++){
      int n = base + t;
      float outv;
      if (mode[t]==0) outv = hs[t][tid];
      else {
        float r = sigmoidf(giL[t][tid]       + ghL[t][tid]);
        float z = sigmoidf(giL[t][64+tid]    + ghL[t][64+tid]);
        float ng = tanhf  (giL[t][128+tid] + r*ghL[t][128+tid]);
        outv = (1.f - z)*ng + z*hs[t][tid];
      }
      mem_new[n*MEMD+tid] = outv;
    }
  }
}

// ---- fused buildx + q,k,v,skip GEMM, small-thread version.
//      Grid 2048: block = 16 rows x 64 cols (one matrix of q/k/v/skip per block),
//      thread = 1 row x 4 cols. 8 blocks/CU -> 32 waves/CU. ----
__global__ __launch_bounds__(256) void k_qkvs(const int* node_ids, const float* node_feat,
                                              const float* mem_new, const float* WcatT,
                                              const float* bcat, float* qbuf, float* kbuf,
                                              float* vbuf, float* outbuf){
  __shared__ float xs[16][193];   // pad: 192%32==0 would alias banks
  int tid = threadIdx.x;
  int rbase = (blockIdx.x >> 2) * 16;
  int colbase = (blockIdx.x & 3) * 64;
  for (int idx = tid; idx < 16*INGNN; idx += 256){
    int r = idx / INGNN, c = idx % INGNN;
    int nid = node_ids[rbase + r];
    xs[r][c] = (c < EEMB) ? node_feat[nid*EEMB + c] : mem_new[nid*MEMD + (c-EEMB)];
  }
  __syncthreads();
  int r = tid >> 4, c4 = (tid & 15) * 4;
  const float* wp = &WcatT[colbase + c4];
  float4 acc = {0.f,0.f,0.f,0.f};
  #pragma unroll 4
  for (int k=0;k<INGNN;k++){
    float4 w = *(const float4*)&wp[k*256];
    float xv = xs[r][k];
    acc.x += xv*w.x; acc.y += xv*w.y; acc.z += xv*w.z; acc.w += xv*w.w;
  }
  float4 b4 = *(const float4*)&bcat[colbase + c4];
  acc.x += b4.x; acc.y += b4.y; acc.z += b4.z; acc.w += b4.w;
  float* dst = (colbase==0)? qbuf : (colbase==64)? kbuf : (colbase==128)? vbuf : outbuf;
  *(float4*)&dst[(rbase + r)*OUTD + c4] = acc;
}

// ---- edge attr (time-enc | edge_features) @ We^T, small-thread version.
//      Grid 1024: block = 16 edges x 64 cols, thread = 1 edge x 4 cols. ----
__global__ __launch_bounds__(256) void k_edge_e(
    const int* edge_ids, const float* edge_ts, const float* last_update,
    const float* edge_features, const float* time_w, const float* time_b,
    const float* WeT, float* ebuf){
  __shared__ float ea[16][161];   // pad: 160%32==0 would alias banks
  int tid = threadIdx.x;
  int ebase = blockIdx.x * 16;
  for (int idx = tid; idx < 16*EDIM; idx += 256){
    int t = idx / EDIM, c = idx % EDIM;
    int j = ebase + t;
    int eid = edge_ids[j];
    float val;
    if (c < TENC){
      float rel = edge_ts[j] - last_update[eid];
      val = cosf(rel*time_w[c] + time_b[c]);
    } else val = edge_features[eid*EEMB + (c-TENC)];
    ea[t][c] = val;
  }
  __syncthreads();
  int r = tid >> 4, c4 = (tid & 15) * 4;
  const float* wp = &WeT[c4];
  float4 acc = {0.f,0.f,0.f,0.f};
  #pragma unroll 4
  for (int k=0;k<EDIM;k++){
    float4 w = *(const float4*)&wp[k*64];
    float ev = ea[r][k];
    acc.x += ev*w.x; acc.y += ev*w.y; acc.z += ev*w.z; acc.w += ev*w.w;
  }
  *(float4*)&ebuf[(ebase + r)*OUTD + c4] = acc;
}

// ---- per-edge score -> p = exp(score); fused den: non-row-0 direct atomics
//      (chain <= ~18), row-0 per-block partial to scratch (no chain). ----
__global__ void k_score(const int* edge_index, const int* first_pos,
                        const float* qbuf, const float* kbuf, const float* ebuf,
                        float* pbuf, int* srcpos, int* tgtpos,
                        float* den, float* den0part){
  __shared__ float sden[4];
  int w = threadIdx.x >> 6;
  int j = blockIdx.x*4 + w;
  int c = threadIdx.x & 63;
  int b = j / NEDGE, e = j % NEDGE;
  int vsrc = edge_index[b*2*NEDGE + e];
  int vtgt = edge_index[b*2*NEDGE + NEDGE + e];
  int fs = first_pos[vsrc]; if (fs == 0x7FFFFFFF) fs = 0;
  int ft = first_pos[vtgt]; if (ft == 0x7FFFFFFF) ft = 0;
  float partial = qbuf[ft*OUTD + c] * (kbuf[fs*OUTD + c] + ebuf[j*OUTD + c]);
  #pragma unroll
  for (int off=32; off>0; off>>=1) partial += __shfl_down(partial, off, 64);
  if (c == 0){
    float score = partial * 0.125f;   // / sqrt(64)
    float p = expf(score);            // softmax shift-invariant; scores O(0.1)
    pbuf[j] = p;
    srcpos[j] = fs; tgtpos[j] = ft;
    sden[w] = (ft == 0) ? p : 0.f;
    if (ft != 0) atomicAdd(&den[ft], p);
  }
  __syncthreads();
  if (threadIdx.x == 0) den0part[blockIdx.x] = sden[0]+sden[1]+sden[2]+sden[3];
}

// ---- finalize den[0]: sum 4096 block partials ----
__global__ __launch_bounds__(1024) void k_fin_den(const float* den0part, float* den){
  __shared__ float part[16];
  int tid = threadIdx.x;
  float s = den0part[tid] + den0part[tid+1024] + den0part[tid+2048] + den0part[tid+3072];
  #pragma unroll
  for (int off=32; off>0; off>>=1) s += __shfl_down(s, off, 64);
  if ((tid & 63) == 0) part[tid>>6] = s;
  __syncthreads();
  if (tid == 0){
    float t = 0.f;
    #pragma unroll
    for (int i=0;i<16;i++) t += part[i];
    den[0] = t;
  }
}

// ---- weighted scatter of v_e (skip already in d_out). Edge-parallel: 16 waves/block,
//      4 edges/wave fully unrolled. Row-0 -> per-block partial row (no atomic chain). ----
__global__ __launch_bounds__(1024) void k_out(const int* srcpos, const int* tgtpos,
                                              const float* pbuf, const float* den,
                                              const float* vbuf, const float* ebuf,
                                              float* out, float* out0part){
  __shared__ float acc0[16][64];
  int tid = threadIdx.x;
  int w = tid >> 6, c = tid & 63;
  int jbase = blockIdx.x*64 + w*4;
  float a0 = 0.f;
  #pragma unroll
  for (int i=0;i<4;i++){
    int j = jbase + i;
    int ft = tgtpos[j], fs = srcpos[j];
    float alpha = pbuf[j] / den[ft];
    float val = alpha * (vbuf[fs*OUTD + c] + ebuf[j*OUTD + c]);
    if (ft == 0) a0 += val;                 // wave-uniform branch
    else atomicAdd(&out[ft*OUTD + c], val);
  }
  acc0[w][c] = a0;
  __syncthreads();
  if (w == 0){
    float t = 0.f;
    #pragma unroll
    for (int i=0;i<16;i++) t += acc0[i][c];
    out0part[blockIdx.x*64 + c] = t;
  }
}

// ---- finalize out row 0: sum 256 partial rows (single writer -> non-atomic add) ----
__global__ __launch_bounds__(1024) void k_fin_out(const float* out0part, float* out){
  __shared__ float part[16][64];
  int tid = threadIdx.x;
  int w = tid >> 6, c = tid & 63;
  float s = 0.f;
  #pragma unroll
  for (int i=0;i<16;i++) s += out0part[(w + i*16)*64 + c];
  part[w][c] = s;
  __syncthreads();
  if (w == 0){
    float t = 0.f;
    #pragma unroll
    for (int i=0;i<16;i++) t += part[i][c];
    out[c] += t;
  }
}

extern "C" void kernel_launch(void* const* d_in, const int* in_sizes, int n_in,
                              void* d_out, int out_size, void* d_ws, size_t ws_size,
                              hipStream_t stream){
  const int*   ev_type      = (const int*)  d_in[0];
  const int*   src_ids      = (const int*)  d_in[1];
  const float* src_mask     = (const float*)d_in[2];
  const int*   dst_ids      = (const int*)  d_in[3];
  const float* dst_mask     = (const float*)d_in[4];
  const int*   ev_edge      = (const int*)  d_in[5];
  const float* ev_emb       = (const float*)d_in[6];
  const float* ev_ts        = (const float*)d_in[7];
  const int*   node_ids     = (const int*)  d_in[8];
  const int*   edge_ids     = (const int*)  d_in[9];
  const int*   edge_index   = (const int*)  d_in[10];
  const float* edge_ts      = (const float*)d_in[11];
  const float* memory       = (const float*)d_in[12];
  const float* last_update  = (const float*)d_in[13];
  const float* node_feat    = (const float*)d_in[14];
  const float* edge_feat    = (const float*)d_in[15];
  const float* type_emb     = (const float*)d_in[16];
  const float* time_w       = (const float*)d_in[17];
  const float* time_b       = (const float*)d_in[18];
  const float* gru_w_ih     = (const float*)d_in[19];
  const float* gru_w_hh     = (const float*)d_in[20];
  const float* gru_b_ih     = (const float*)d_in[21];
  const float* gru_b_hh     = (const float*)d_in[22];
  const float* Wq  = (const float*)d_in[23]; const float* bq    = (const float*)d_in[24];
  const float* Wk  = (const float*)d_in[25]; const float* bk    = (const float*)d_in[26];
  const float* Wv  = (const float*)d_in[27]; const float* bv    = (const float*)d_in[28];
  const float* We  = (const float*)d_in[29];
  const float* Wsk = (const float*)d_in[30]; const float* bskip = (const float*)d_in[31];
  float* out = (float*)d_out;

  float* ws = (float*)d_ws;
  size_t off = 0;
  // --- zeroed span (accumulators) ---
  float* agg_src = ws + off; off += (size_t)MAXN*MSG;
  float* agg_dst = ws + off; off += (size_t)MAXN*MSG;
  int* cnt_src   = (int*)(ws + off); off += MAXN;
  int* cnt_dst   = (int*)(ws + off); off += MAXN;
  int* present_s = (int*)(ws + off); off += MAXN;
  int* present_d = (int*)(ws + off); off += MAXN;
  float* den     = ws + off; off += BN;
  int n_zero = (int)off;
  // --- rest (fully overwritten each call) ---
  int* first_pos = (int*)(ws + off); off += MAXN;
  float* mem_new = ws + off; off += (size_t)MAXN*MEMD;
  float* qbuf    = ws + off; off += (size_t)BN*OUTD;
  float* kbuf    = ws + off; off += (size_t)BN*OUTD;
  float* vbuf    = ws + off; off += (size_t)BN*OUTD;
  float* ebuf    = ws + off; off += (size_t)BE*OUTD;
  float* pbuf    = ws + off; off += BE;
  int* srcpos    = (int*)(ws + off); off += BE;
  int* tgtpos    = (int*)(ws + off); off += BE;
  float* den0part= ws + off; off += 4096;
  float* out0part= ws + off; off += 256*64;
  float* wihT    = ws + off; off += (size_t)MSG*192;
  float* whhT    = ws + off; off += (size_t)MEMD*192;
  float* WcatT   = ws + off; off += (size_t)INGNN*256;
  float* WeT     = ws + off; off += (size_t)EDIM*64;
  float* bcat    = ws + off; off += 256;

  k_init<<<2048, 256, 0, stream>>>(ws, n_zero, first_pos,
                                   gru_w_ih, gru_w_hh, Wq, Wk, Wv, Wsk, We,
                                   bq, bk, bv, bskip,
                                   wihT, whhT, WcatT, WeT, bcat);
  k_msg<<<SS, 320, 0, stream>>>(ev_type, src_ids, src_mask, dst_ids, dst_mask, ev_edge,
                                ev_emb, ev_ts, memory, last_update, type_emb,
                                time_w, time_b, agg_src, agg_dst, cnt_src, cnt_dst);
  k_first<<<BN/256, 256, 0, stream>>>(node_ids, first_pos, src_ids, dst_ids,
                                      present_s, present_d);
  k_gru<<<MAXN/NT, 192, 0, stream>>>(agg_src, agg_dst, cnt_src, cnt_dst,
                                     present_s, present_d, memory,
                                     wihT, whhT, gru_b_ih, gru_b_hh, mem_new);
  k_qkvs<<<(BN/16)*4, 256, 0, stream>>>(node_ids, node_feat, mem_new, WcatT, bcat,
                                        qbuf, kbuf, vbuf, out);
  k_edge_e<<<BE/16, 256, 0, stream>>>(edge_ids, edge_ts, last_update, edge_feat,
                                      time_w, time_b, WeT, ebuf);
  k_score<<<BE/4, 256, 0, stream>>>(edge_index, first_pos, qbuf, kbuf, ebuf,
                                    pbuf, srcpos, tgtpos, den, den0part);
  k_fin_den<<<1, 1024, 0, stream>>>(den0part, den);
  k_out<<<256, 1024, 0, stream>>>(srcpos, tgtpos, pbuf, den, vbuf, ebuf, out, out0part);
  k_fin_out<<<1, 1024, 0, stream>>>(out0part, out);
}

// Round 5
// 130.609 us; speedup vs baseline: 1.1215x; 1.1215x over previous
//
#include <hip/hip_runtime.h>
#include <math.h>

// ---- problem dims ----
#define BB 8
#define SS 512
#define NNODE 1024
#define NEDGE 2048
#define MAXN 4096
#define MAXE 8192
#define TYPED 16
#define MEMD 64
#define TENC 32
#define EEMB 128
#define OUTD 64
#define MSG 304      // 16+64+64+32+128
#define INGNN 192    // 128+64
#define EDIM 160     // 32+128
#define BN 8192      // B*N
#define BE 16384     // B*E

__device__ __forceinline__ float sigmoidf(float x){ return 1.f/(1.f + expf(-x)); }

// ---- init: zero accumulator span (float4), first_pos=INT_MAX, weight transposes ----
__global__ void k_init(float* zero_base, int n_zero, int* first_pos,
                       const float* w_ih, const float* w_hh, const float* Wq,
                       const float* Wk, const float* Wv, const float* Wskip,
                       const float* We, const float* bq, const float* bk,
                       const float* bv, const float* bskip,
                       float* wihT, float* whhT, float* WcatT, float* WeT, float* bcat){
  int i = blockIdx.x*blockDim.x + threadIdx.x;
  int stride = gridDim.x*blockDim.x;
  float4* z4 = (float4*)zero_base;
  int n4 = n_zero >> 2;
  float4 zero = {0.f,0.f,0.f,0.f};
  for (int t=i; t<n4; t+=stride) z4[t] = zero;
  for (int t=i; t<MAXN; t+=stride) first_pos[t] = 0x7FFFFFFF;
  int j = i;
  const int n0 = 192*MSG;
  if (j < n0){ int r=j/MSG, c=j%MSG; wihT[c*192+r] = w_ih[j]; }
  else {
    j -= n0;
    if (j < 192*64){ int r=j/64, c=j%64; whhT[c*192+r] = w_hh[j]; }
    else {
      j -= 192*64;
      if (j < 4*64*192){
        int o = j/(64*192); int rem = j%(64*192); int q=rem/192, k=rem%192;
        const float* W = (o==0)?Wq:(o==1)?Wk:(o==2)?Wv:Wskip;
        WcatT[k*256 + o*64 + q] = W[rem];
      } else {
        j -= 4*64*192;
        if (j < 64*EDIM){ int q=j/EDIM, k=j%EDIM; WeT[k*64+q] = We[j]; }
        else {
          j -= 64*EDIM;
          if (j < 256){
            const float* b = (j<64)?bq:(j<128)?bk:(j<192)?bv:bskip;
            bcat[j] = b[j&63];
          }
        }
      }
    }
  }
}

// ---- fused: messages for batch 0 (blocks < SS) + first-pos/presence (rest) ----
__global__ void k_msg_first(const int* ev_type, const int* src_ids, const float* src_mask,
                            const int* dst_ids, const float* dst_mask, const int* ev_edge,
                            const float* ev_emb, const float* ev_ts, const float* memory,
                            const float* last_update, const float* type_emb,
                            const float* time_w, const float* time_b,
                            float* agg_src, float* agg_dst, int* cnt_src, int* cnt_dst,
                            const int* node_ids, int* first_pos, int* ps, int* pd){
  int bb = blockIdx.x;
  if (bb < SS){
    int s = bb;
    int et = ev_type[s];
    int sid = src_ids[s], did = dst_ids[s];
    float sm = src_mask[s], dm = dst_mask[s];
    float ts = ev_ts[s];
    float ns = (et >= 3) ? 1.f : 0.f;
    float ine = (et == 3 || et == 4) ? 1.f : 0.f;
    float rel = ts - last_update[ev_edge[s]] * dm;
    float tin = ts*ine + rel*dm;
    int d = threadIdx.x;
    if (d < MSG){
      float vs, vd;
      if (d < TYPED){ float t = type_emb[et*TYPED + d]; vs = t; vd = t; }
      else if (d < 80){ int c=d-16;  vs = memory[sid*MEMD+c]*sm; vd = memory[did*MEMD+c]*dm; }
      else if (d < 144){ int c=d-80; vs = memory[did*MEMD+c]*dm; vd = memory[sid*MEMD+c]*sm; }
      else if (d < 176){ int c=d-144; float ce = cosf(tin*time_w[c]+time_b[c])*ns; vs=ce; vd=ce; }
      else { float e = ev_emb[s*EEMB + (d-176)]; vs=e; vd=e; }
      atomicAdd(&agg_src[sid*MSG+d], vs*ns);
      atomicAdd(&agg_dst[did*MSG+d], vd*dm);
    }
    if (d == MSG){ atomicAdd(&cnt_src[sid], 1); atomicAdd(&cnt_dst[did], 1); }
  } else {
    int i = (bb - SS)*320 + threadIdx.x;
    if (i < BN) atomicMin(&first_pos[node_ids[i]], i);
    if (i < BB*SS){ ps[src_ids[i]] = 1; pd[dst_ids[i]] = 1; }
  }
}

// ---- GRU memory update (one GRU per node; dst wins over src).
//      Block-level skip of the 304-k input GEMM when all NT nodes have cnt==0
//      (their agg rows are exactly zero -> gi = b_ih). ----
#define NT 4
__global__ __launch_bounds__(192) void k_gru(
    const float* agg_src, const float* agg_dst, const int* cnt_src, const int* cnt_dst,
    const int* ps, const int* pd, const float* memory,
    const float* wihT, const float* whhT, const float* b_ih, const float* b_hh,
    float* mem_new){
  __shared__ float xs[NT][MSG];
  __shared__ float hs[NT][MEMD];
  __shared__ float giL[NT][192];
  __shared__ float ghL[NT][192];
  __shared__ int mode[NT];
  __shared__ int cshare[NT];
  int tid = threadIdx.x;
  int base = blockIdx.x * NT;
  if (tid < NT){
    int n = base + tid;
    int m = pd[n] ? 2 : (ps[n] ? 1 : 0);
    mode[tid] = m;
    cshare[tid] = (m==2) ? cnt_dst[n] : ((m==1) ? cnt_src[n] : 0);
  }
  __syncthreads();
  int any = cshare[0] | cshare[1] | cshare[2] | cshare[3];
  for (int idx = tid; idx < NT*MEMD; idx += 192){
    int t = idx / MEMD, d = idx % MEMD;
    hs[t][d] = memory[(base+t)*MEMD + d];
  }
  if (any){
    for (int idx = tid; idx < NT*MSG; idx += 192){
      int t = idx / MSG, d = idx % MSG;
      int n = base + t;
      int c = cshare[t];
      float x = 0.f;
      if (c > 0){
        const float* agg = (mode[t]==2) ? agg_dst : agg_src;
        x = agg[n*MSG+d] / (float)c;
      }
      xs[t][d] = x;
    }
  }
  __syncthreads();
  float bi = b_ih[tid];
  if (any){
    float acc[NT];
    #pragma unroll
    for (int t=0;t<NT;t++) acc[t] = 0.f;
    #pragma unroll 4
    for (int k=0;k<MSG;k++){
      float w = wihT[k*192 + tid];
      #pragma unroll
      for (int t=0;t<NT;t++) acc[t] += w * xs[t][k];
    }
    #pragma unroll
    for (int t=0;t<NT;t++) giL[t][tid] = acc[t] + bi;
  } else {
    #pragma unroll
    for (int t=0;t<NT;t++) giL[t][tid] = bi;
  }
  {
    float acc[NT];
    #pragma unroll
    for (int t=0;t<NT;t++) acc[t] = 0.f;
    #pragma unroll 4
    for (int k=0;k<MEMD;k++){
      float w = whhT[k*192 + tid];
      #pragma unroll
      for (int t=0;t<NT;t++) acc[t] += w * hs[t][k];
    }
    float bh = b_hh[tid];
    #pragma unroll
    for (int t=0;t<NT;t++) ghL[t][tid] = acc[t] + bh;
  }
  __syncthreads();
  if (tid < MEMD){
    #pragma unroll
    for (int t=0;t<NT;t++){
      int n = base + t;
      float outv;
      if (mode[t]==0) outv = hs[t][tid];
      else {
        float r = sigmoidf(giL[t][tid]       + ghL[t][tid]);
        float z = sigmoidf(giL[t][64+tid]    + ghL[t][64+tid]);
        float ng = tanhf  (giL[t][128+tid] + r*ghL[t][128+tid]);
        outv = (1.f - z)*ng + z*hs[t][tid];
      }
      mem_new[n*MEMD+tid] = outv;
    }
  }
}

// ---- fused buildx + q,k,v,skip GEMM: 512 blocks x 512 threads.
//      Block = 16 rows x 256 cols (full W -> min weight re-reads),
//      thread = 1 row x 8 cols (8-deep ILP), 16 waves/CU. ----
__global__ __launch_bounds__(512) void k_qkvs(const int* node_ids, const float* node_feat,
                                              const float* mem_new, const float* WcatT,
                                              const float* bcat, float* qbuf, float* kbuf,
                                              float* vbuf, float* outbuf){
  __shared__ float xs[16][193];   // pad: 192%32==0 would alias banks
  int tid = threadIdx.x;
  int rbase = blockIdx.x * 16;
  for (int idx = tid; idx < 16*INGNN; idx += 512){
    int r = idx / INGNN, c = idx % INGNN;
    int nid = node_ids[rbase + r];
    xs[r][c] = (c < EEMB) ? node_feat[nid*EEMB + c] : mem_new[nid*MEMD + (c-EEMB)];
  }
  __syncthreads();
  int r = tid >> 5;            // 16 rows
  int c8 = (tid & 31) * 8;     // 256 cols / 8
  float a0=0.f,a1=0.f,a2=0.f,a3=0.f,a4=0.f,a5=0.f,a6=0.f,a7=0.f;
  const float* wp = &WcatT[c8];
  #pragma unroll 4
  for (int k=0;k<INGNN;k++){
    float4 w0 = *(const float4*)&wp[k*256];
    float4 w1 = *(const float4*)&wp[k*256 + 4];
    float xv = xs[r][k];
    a0 += xv*w0.x; a1 += xv*w0.y; a2 += xv*w0.z; a3 += xv*w0.w;
    a4 += xv*w1.x; a5 += xv*w1.y; a6 += xv*w1.z; a7 += xv*w1.w;
  }
  float4 b0 = *(const float4*)&bcat[c8];
  float4 b1 = *(const float4*)&bcat[c8+4];
  float4 o0 = {a0+b0.x, a1+b0.y, a2+b0.z, a3+b0.w};
  float4 o1 = {a4+b1.x, a5+b1.y, a6+b1.z, a7+b1.w};
  int sel = c8 >> 6;
  float* dst = (sel==0)? qbuf : (sel==1)? kbuf : (sel==2)? vbuf : outbuf;
  int cc = c8 & 63;
  *(float4*)&dst[(rbase + r)*OUTD + cc]     = o0;
  *(float4*)&dst[(rbase + r)*OUTD + cc + 4] = o1;
}

// ---- edge attr (time-enc | edge_features) @ We^T (R3 structure) ----
__global__ __launch_bounds__(256) void k_edge_e(
    const int* edge_ids, const float* edge_ts, const float* last_update,
    const float* edge_features, const float* time_w, const float* time_b,
    const float* WeT, float* ebuf){
  __shared__ float ea[16][EDIM];
  int tid = threadIdx.x;
  int ebase = blockIdx.x * 16;
  for (int idx = tid; idx < 16*EDIM; idx += 256){
    int t = idx / EDIM, c = idx % EDIM;
    int j = ebase + t;
    int eid = edge_ids[j];
    float val;
    if (c < TENC){
      float rel = edge_ts[j] - last_update[eid];
      val = cosf(rel*time_w[c] + time_b[c]);
    } else val = edge_features[eid*EEMB + (c-TENC)];
    ea[t][c] = val;
  }
  __syncthreads();
  int g = tid >> 6, j = tid & 63;
  float acc[4];
  #pragma unroll
  for (int t=0;t<4;t++) acc[t]=0.f;
  #pragma unroll 4
  for (int k=0;k<EDIM;k++){
    float w = WeT[k*64 + j];
    #pragma unroll
    for (int t=0;t<4;t++) acc[t] += w * ea[g*4+t][k];
  }
  #pragma unroll
  for (int t=0;t<4;t++) ebuf[(ebase+g*4+t)*OUTD + j] = acc[t];
}

// ---- per-edge score -> p = exp(score); fused den: non-row-0 direct atomics
//      (chain <= ~18), row-0 per-block partial to scratch (no chain). ----
__global__ void k_score(const int* edge_index, const int* first_pos,
                        const float* qbuf, const float* kbuf, const float* ebuf,
                        float* pbuf, int* srcpos, int* tgtpos,
                        float* den, float* den0part){
  __shared__ float sden[4];
  int w = threadIdx.x >> 6;
  int j = blockIdx.x*4 + w;
  int c = threadIdx.x & 63;
  int b = j / NEDGE, e = j % NEDGE;
  int vsrc = edge_index[b*2*NEDGE + e];
  int vtgt = edge_index[b*2*NEDGE + NEDGE + e];
  int fs = first_pos[vsrc]; if (fs == 0x7FFFFFFF) fs = 0;
  int ft = first_pos[vtgt]; if (ft == 0x7FFFFFFF) ft = 0;
  float partial = qbuf[ft*OUTD + c] * (kbuf[fs*OUTD + c] + ebuf[j*OUTD + c]);
  #pragma unroll
  for (int off=32; off>0; off>>=1) partial += __shfl_down(partial, off, 64);
  if (c == 0){
    float score = partial * 0.125f;   // / sqrt(64)
    float p = expf(score);            // softmax shift-invariant; scores O(0.1)
    pbuf[j] = p;
    srcpos[j] = fs; tgtpos[j] = ft;
    sden[w] = (ft == 0) ? p : 0.f;
    if (ft != 0) atomicAdd(&den[ft], p);
  }
  __syncthreads();
  if (threadIdx.x == 0) den0part[blockIdx.x] = sden[0]+sden[1]+sden[2]+sden[3];
}

// ---- finalize den[0]: sum 4096 block partials ----
__global__ __launch_bounds__(1024) void k_fin_den(const float* den0part, float* den){
  __shared__ float part[16];
  int tid = threadIdx.x;
  float s = den0part[tid] + den0part[tid+1024] + den0part[tid+2048] + den0part[tid+3072];
  #pragma unroll
  for (int off=32; off>0; off>>=1) s += __shfl_down(s, off, 64);
  if ((tid & 63) == 0) part[tid>>6] = s;
  __syncthreads();
  if (tid == 0){
    float t = 0.f;
    #pragma unroll
    for (int i=0;i<16;i++) t += part[i];
    den[0] = t;
  }
}

// ---- weighted scatter of v_e (skip already in d_out). Edge-parallel: 16 waves/block,
//      4 edges/wave fully unrolled. Row-0 -> per-block partial row (no atomic chain). ----
__global__ __launch_bounds__(1024) void k_out(const int* srcpos, const int* tgtpos,
                                              const float* pbuf, const float* den,
                                              const float* vbuf, const float* ebuf,
                                              float* out, float* out0part){
  __shared__ float acc0[16][64];
  int tid = threadIdx.x;
  int w = tid >> 6, c = tid & 63;
  int jbase = blockIdx.x*64 + w*4;
  float a0 = 0.f;
  #pragma unroll
  for (int i=0;i<4;i++){
    int j = jbase + i;
    int ft = tgtpos[j], fs = srcpos[j];
    float alpha = pbuf[j] / den[ft];
    float val = alpha * (vbuf[fs*OUTD + c] + ebuf[j*OUTD + c]);
    if (ft == 0) a0 += val;                 // wave-uniform branch
    else atomicAdd(&out[ft*OUTD + c], val);
  }
  acc0[w][c] = a0;
  __syncthreads();
  if (w == 0){
    float t = 0.f;
    #pragma unroll
    for (int i=0;i<16;i++) t += acc0[i][c];
    out0part[blockIdx.x*64 + c] = t;
  }
}

// ---- finalize out row 0: sum 256 partial rows (single writer -> non-atomic add) ----
__global__ __launch_bounds__(1024) void k_fin_out(const float* out0part, float* out){
  __shared__ float part[16][64];
  int tid = threadIdx.x;
  int w = tid >> 6, c = tid & 63;
  float s = 0.f;
  #pragma unroll
  for (int i=0;i<16;i++) s += out0part[(w + i*16)*64 + c];
  part[w][c] = s;
  __syncthreads();
  if (w == 0){
    float t = 0.f;
    #pragma unroll
    for (int i=0;i<16;i++) t += part[i][c];
    out[c] += t;
  }
}

extern "C" void kernel_launch(void* const* d_in, const int* in_sizes, int n_in,
                              void* d_out, int out_size, void* d_ws, size_t ws_size,
                              hipStream_t stream){
  const int*   ev_type      = (const int*)  d_in[0];
  const int*   src_ids      = (const int*)  d_in[1];
  const float* src_mask     = (const float*)d_in[2];
  const int*   dst_ids      = (const int*)  d_in[3];
  const float* dst_mask     = (const float*)d_in[4];
  const int*   ev_edge      = (const int*)  d_in[5];
  const float* ev_emb       = (const float*)d_in[6];
  const float* ev_ts        = (const float*)d_in[7];
  const int*   node_ids     = (const int*)  d_in[8];
  const int*   edge_ids     = (const int*)  d_in[9];
  const int*   edge_index   = (const int*)  d_in[10];
  const float* edge_ts      = (const float*)d_in[11];
  const float* memory       = (const float*)d_in[12];
  const float* last_update  = (const float*)d_in[13];
  const float* node_feat    = (const float*)d_in[14];
  const float* edge_feat    = (const float*)d_in[15];
  const float* type_emb     = (const float*)d_in[16];
  const float* time_w       = (const float*)d_in[17];
  const float* time_b       = (const float*)d_in[18];
  const float* gru_w_ih     = (const float*)d_in[19];
  const float* gru_w_hh     = (const float*)d_in[20];
  const float* gru_b_ih     = (const float*)d_in[21];
  const float* gru_b_hh     = (const float*)d_in[22];
  const float* Wq  = (const float*)d_in[23]; const float* bq    = (const float*)d_in[24];
  const float* Wk  = (const float*)d_in[25]; const float* bk    = (const float*)d_in[26];
  const float* Wv  = (const float*)d_in[27]; const float* bv    = (const float*)d_in[28];
  const float* We  = (const float*)d_in[29];
  const float* Wsk = (const float*)d_in[30]; const float* bskip = (const float*)d_in[31];
  float* out = (float*)d_out;

  float* ws = (float*)d_ws;
  size_t off = 0;
  // --- zeroed span (accumulators) ---
  float* agg_src = ws + off; off += (size_t)MAXN*MSG;
  float* agg_dst = ws + off; off += (size_t)MAXN*MSG;
  int* cnt_src   = (int*)(ws + off); off += MAXN;
  int* cnt_dst   = (int*)(ws + off); off += MAXN;
  int* present_s = (int*)(ws + off); off += MAXN;
  int* present_d = (int*)(ws + off); off += MAXN;
  float* den     = ws + off; off += BN;
  int n_zero = (int)off;
  // --- rest (fully overwritten each call) ---
  int* first_pos = (int*)(ws + off); off += MAXN;
  float* mem_new = ws + off; off += (size_t)MAXN*MEMD;
  float* qbuf    = ws + off; off += (size_t)BN*OUTD;
  float* kbuf    = ws + off; off += (size_t)BN*OUTD;
  float* vbuf    = ws + off; off += (size_t)BN*OUTD;
  float* ebuf    = ws + off; off += (size_t)BE*OUTD;
  float* pbuf    = ws + off; off += BE;
  int* srcpos    = (int*)(ws + off); off += BE;
  int* tgtpos    = (int*)(ws + off); off += BE;
  float* den0part= ws + off; off += 4096;
  float* out0part= ws + off; off += 256*64;
  float* wihT    = ws + off; off += (size_t)MSG*192;
  float* whhT    = ws + off; off += (size_t)MEMD*192;
  float* WcatT   = ws + off; off += (size_t)INGNN*256;
  float* WeT     = ws + off; off += (size_t)EDIM*64;
  float* bcat    = ws + off; off += 256;

  k_init<<<2048, 256, 0, stream>>>(ws, n_zero, first_pos,
                                   gru_w_ih, gru_w_hh, Wq, Wk, Wv, Wsk, We,
                                   bq, bk, bv, bskip,
                                   wihT, whhT, WcatT, WeT, bcat);
  k_msg_first<<<SS + (BN + 319)/320, 320, 0, stream>>>(
      ev_type, src_ids, src_mask, dst_ids, dst_mask, ev_edge,
      ev_emb, ev_ts, memory, last_update, type_emb, time_w, time_b,
      agg_src, agg_dst, cnt_src, cnt_dst,
      node_ids, first_pos, present_s, present_d);
  k_gru<<<MAXN/NT, 192, 0, stream>>>(agg_src, agg_dst, cnt_src, cnt_dst,
                                     present_s, present_d, memory,
                                     wihT, whhT, gru_b_ih, gru_b_hh, mem_new);
  k_qkvs<<<BN/16, 512, 0, stream>>>(node_ids, node_feat, mem_new, WcatT, bcat,
                                    qbuf, kbuf, vbuf, out);
  k_edge_e<<<BE/16, 256, 0, stream>>>(edge_ids, edge_ts, last_update, edge_feat,
                                      time_w, time_b, WeT, ebuf);
  k_score<<<BE/4, 256, 0, stream>>>(edge_index, first_pos, qbuf, kbuf, ebuf,
                                    pbuf, srcpos, tgtpos, den, den0part);
  k_fin_den<<<1, 1024, 0, stream>>>(den0part, den);
  k_out<<<256, 1024, 0, stream>>>(srcpos, tgtpos, pbuf, den, vbuf, ebuf, out, out0part);
  k_fin_out<<<1, 1024, 0, stream>>>(out0part, out);
}

// Round 6
// 98.991 us; speedup vs baseline: 1.4797x; 1.3194x over previous
//
#include <hip/hip_runtime.h>
#include <math.h>

// ---- problem dims ----
#define BB 8
#define SS 512
#define NNODE 1024
#define NEDGE 2048
#define MAXN 4096
#define MAXE 8192
#define TYPED 16
#define MEMD 64
#define TENC 32
#define EEMB 128
#define OUTD 64
#define MSG 304      // 16+64+64+32+128
#define INGNN 192    // 128+64
#define EDIM 160     // 32+128
#define BN 8192      // B*N
#define BE 16384     // B*E

__device__ __forceinline__ float sigmoidf(float x){ return 1.f/(1.f + expf(-x)); }

// ---- init: zero accumulator span (float4), first_pos=INT_MAX, weight transposes ----
__global__ void k_init(float* zero_base, int n_zero, int* first_pos,
                       const float* w_ih, const float* w_hh, const float* Wq,
                       const float* Wk, const float* Wv, const float* Wskip,
                       const float* We, const float* bq, const float* bk,
                       const float* bv, const float* bskip,
                       float* wihT, float* whhT, float* WcatT, float* WeT, float* bcat){
  int i = blockIdx.x*blockDim.x + threadIdx.x;
  int stride = gridDim.x*blockDim.x;
  float4* z4 = (float4*)zero_base;
  int n4 = n_zero >> 2;
  float4 zero = {0.f,0.f,0.f,0.f};
  for (int t=i; t<n4; t+=stride) z4[t] = zero;
  for (int t=i; t<MAXN; t+=stride) first_pos[t] = 0x7FFFFFFF;
  int j = i;
  const int n0 = 192*MSG;
  if (j < n0){ int r=j/MSG, c=j%MSG; wihT[c*192+r] = w_ih[j]; }
  else {
    j -= n0;
    if (j < 192*64){ int r=j/64, c=j%64; whhT[c*192+r] = w_hh[j]; }
    else {
      j -= 192*64;
      if (j < 4*64*192){
        int o = j/(64*192); int rem = j%(64*192); int q=rem/192, k=rem%192;
        const float* W = (o==0)?Wq:(o==1)?Wk:(o==2)?Wv:Wskip;
        WcatT[k*256 + o*64 + q] = W[rem];
      } else {
        j -= 4*64*192;
        if (j < 64*EDIM){ int q=j/EDIM, k=j%EDIM; WeT[k*64+q] = We[j]; }
        else {
          j -= 64*EDIM;
          if (j < 256){
            const float* b = (j<64)?bq:(j<128)?bk:(j<192)?bv:bskip;
            bcat[j] = b[j&63];
          }
        }
      }
    }
  }
}

// ---- fused: messages for batch 0 (blocks < SS) + first-pos/presence (rest) ----
__global__ void k_msg_first(const int* ev_type, const int* src_ids, const float* src_mask,
                            const int* dst_ids, const float* dst_mask, const int* ev_edge,
                            const float* ev_emb, const float* ev_ts, const float* memory,
                            const float* last_update, const float* type_emb,
                            const float* time_w, const float* time_b,
                            float* agg_src, float* agg_dst, int* cnt_src, int* cnt_dst,
                            const int* node_ids, int* first_pos, int* ps, int* pd){
  int bb = blockIdx.x;
  if (bb < SS){
    int s = bb;
    int et = ev_type[s];
    int sid = src_ids[s], did = dst_ids[s];
    float sm = src_mask[s], dm = dst_mask[s];
    float ts = ev_ts[s];
    float ns = (et >= 3) ? 1.f : 0.f;
    float ine = (et == 3 || et == 4) ? 1.f : 0.f;
    float rel = ts - last_update[ev_edge[s]] * dm;
    float tin = ts*ine + rel*dm;
    int d = threadIdx.x;
    if (d < MSG){
      float vs, vd;
      if (d < TYPED){ float t = type_emb[et*TYPED + d]; vs = t; vd = t; }
      else if (d < 80){ int c=d-16;  vs = memory[sid*MEMD+c]*sm; vd = memory[did*MEMD+c]*dm; }
      else if (d < 144){ int c=d-80; vs = memory[did*MEMD+c]*dm; vd = memory[sid*MEMD+c]*sm; }
      else if (d < 176){ int c=d-144; float ce = cosf(tin*time_w[c]+time_b[c])*ns; vs=ce; vd=ce; }
      else { float e = ev_emb[s*EEMB + (d-176)]; vs=e; vd=e; }
      atomicAdd(&agg_src[sid*MSG+d], vs*ns);
      atomicAdd(&agg_dst[did*MSG+d], vd*dm);
    }
    if (d == MSG){ atomicAdd(&cnt_src[sid], 1); atomicAdd(&cnt_dst[did], 1); }
  } else {
    int i = (bb - SS)*320 + threadIdx.x;
    if (i < BN) atomicMin(&first_pos[node_ids[i]], i);
    if (i < BB*SS){ ps[src_ids[i]] = 1; pd[dst_ids[i]] = 1; }
  }
}

// ---- GRU memory update (one GRU per node; dst wins over src).
//      Block-level skip of the 304-k input GEMM when all NT nodes have cnt==0. ----
#define NT 4
__global__ __launch_bounds__(192) void k_gru(
    const float* agg_src, const float* agg_dst, const int* cnt_src, const int* cnt_dst,
    const int* ps, const int* pd, const float* memory,
    const float* wihT, const float* whhT, const float* b_ih, const float* b_hh,
    float* mem_new){
  __shared__ float xs[NT][MSG];
  __shared__ float hs[NT][MEMD];
  __shared__ float giL[NT][192];
  __shared__ float ghL[NT][192];
  __shared__ int mode[NT];
  __shared__ int cshare[NT];
  int tid = threadIdx.x;
  int base = blockIdx.x * NT;
  if (tid < NT){
    int n = base + tid;
    int m = pd[n] ? 2 : (ps[n] ? 1 : 0);
    mode[tid] = m;
    cshare[tid] = (m==2) ? cnt_dst[n] : ((m==1) ? cnt_src[n] : 0);
  }
  __syncthreads();
  int any = cshare[0] | cshare[1] | cshare[2] | cshare[3];
  for (int idx = tid; idx < NT*MEMD; idx += 192){
    int t = idx / MEMD, d = idx % MEMD;
    hs[t][d] = memory[(base+t)*MEMD + d];
  }
  if (any){
    for (int idx = tid; idx < NT*MSG; idx += 192){
      int t = idx / MSG, d = idx % MSG;
      int n = base + t;
      int c = cshare[t];
      float x = 0.f;
      if (c > 0){
        const float* agg = (mode[t]==2) ? agg_dst : agg_src;
        x = agg[n*MSG+d] / (float)c;
      }
      xs[t][d] = x;
    }
  }
  __syncthreads();
  float bi = b_ih[tid];
  if (any){
    float acc[NT];
    #pragma unroll
    for (int t=0;t<NT;t++) acc[t] = 0.f;
    #pragma unroll 4
    for (int k=0;k<MSG;k++){
      float w = wihT[k*192 + tid];
      #pragma unroll
      for (int t=0;t<NT;t++) acc[t] += w * xs[t][k];
    }
    #pragma unroll
    for (int t=0;t<NT;t++) giL[t][tid] = acc[t] + bi;
  } else {
    #pragma unroll
    for (int t=0;t<NT;t++) giL[t][tid] = bi;
  }
  {
    float acc[NT];
    #pragma unroll
    for (int t=0;t<NT;t++) acc[t] = 0.f;
    #pragma unroll 4
    for (int k=0;k<MEMD;k++){
      float w = whhT[k*192 + tid];
      #pragma unroll
      for (int t=0;t<NT;t++) acc[t] += w * hs[t][k];
    }
    float bh = b_hh[tid];
    #pragma unroll
    for (int t=0;t<NT;t++) ghL[t][tid] = acc[t] + bh;
  }
  __syncthreads();
  if (tid < MEMD){
    #pragma unroll
    for (int t=0;t<NT;t++){
      int n = base + t;
      float outv;
      if (mode[t]==0) outv = hs[t][tid];
      else {
        float r = sigmoidf(giL[t][tid]       + ghL[t][tid]);
        float z = sigmoidf(giL[t][64+tid]    + ghL[t][64+tid]);
        float ng = tanhf  (giL[t][128+tid] + r*ghL[t][128+tid]);
        outv = (1.f - z)*ng + z*hs[t][tid];
      }
      mem_new[n*MEMD+tid] = outv;
    }
  }
}

// ---- fused buildx + q,k,v,skip GEMM, LDS-resident version.
//      Grid 512 = 128 row-groups x 4 col-groups. Block = 64 rows x 64 cols,
//      256 threads, 4x4 register tile. K chunked x96; BOTH x and W live in LDS,
//      inner loop = 2 ds_read_b128 + 16 v_fma (no global loads -> no L2 latency). ----
#define QK_CH 96
__global__ __launch_bounds__(256) void k_qkvs(const int* node_ids, const float* node_feat,
                                              const float* mem_new, const float* WcatT,
                                              const float* bcat, float* qbuf, float* kbuf,
                                              float* vbuf, float* outbuf){
  __shared__ float xs_t[QK_CH][68];   // [k][row], pad 68 (16B-aligned rows, bank spread)
  __shared__ float wls[QK_CH][64];    // [k][col]
  int tid = threadIdx.x;
  int rg = blockIdx.x >> 2, cg = blockIdx.x & 3;
  int rbase = rg * 64;
  int rr = tid & 63, qq = tid >> 6;        // staging: row rr, k-quarter qq
  int nid = node_ids[rbase + rr];
  int tr = tid >> 4, tc = tid & 15;        // compute: rows tr*4.., cols tc*4..
  float4 acc[4];
  #pragma unroll
  for (int i=0;i<4;i++) acc[i] = (float4){0.f,0.f,0.f,0.f};

  for (int kc = 0; kc < 2; kc++){
    // stage x^T: thread -> 24 k-values of row rr
    #pragma unroll 6
    for (int m = 0; m < 24; m++){
      int kk = qq*24 + m;
      int k  = kc*QK_CH + kk;
      float v = (k < EEMB) ? node_feat[nid*EEMB + k] : mem_new[nid*MEMD + (k-EEMB)];
      xs_t[kk][rr] = v;
    }
    // stage W chunk: 96x16 float4 groups
    #pragma unroll
    for (int it = 0; it < 6; it++){
      int idx = tid + it*256;
      int kk = idx >> 4, c4 = (idx & 15) * 4;
      *(float4*)&wls[kk][c4] = *(const float4*)&WcatT[(kc*QK_CH + kk)*256 + cg*64 + c4];
    }
    __syncthreads();
    #pragma unroll 4
    for (int kk = 0; kk < QK_CH; kk++){
      float4 xv = *(const float4*)&xs_t[kk][tr*4];
      float4 wv = *(const float4*)&wls[kk][tc*4];
      acc[0].x += xv.x*wv.x; acc[0].y += xv.x*wv.y; acc[0].z += xv.x*wv.z; acc[0].w += xv.x*wv.w;
      acc[1].x += xv.y*wv.x; acc[1].y += xv.y*wv.y; acc[1].z += xv.y*wv.z; acc[1].w += xv.y*wv.w;
      acc[2].x += xv.z*wv.x; acc[2].y += xv.z*wv.y; acc[2].z += xv.z*wv.z; acc[2].w += xv.z*wv.w;
      acc[3].x += xv.w*wv.x; acc[3].y += xv.w*wv.y; acc[3].z += xv.w*wv.z; acc[3].w += xv.w*wv.w;
    }
    __syncthreads();
  }
  float4 b4 = *(const float4*)&bcat[cg*64 + tc*4];
  float* dst = (cg==0)? qbuf : (cg==1)? kbuf : (cg==2)? vbuf : outbuf;
  #pragma unroll
  for (int i=0;i<4;i++){
    float4 o = {acc[i].x+b4.x, acc[i].y+b4.y, acc[i].z+b4.z, acc[i].w+b4.w};
    *(float4*)&dst[(rbase + tr*4 + i)*OUTD + tc*4] = o;
  }
}

// ---- edge attr (time-enc | edge_features) @ We^T, LDS-resident version.
//      Grid 256. Block = 64 edges x 64 cols, K chunked x80. ----
#define EE_CH 80
__global__ __launch_bounds__(256) void k_edge_e(
    const int* edge_ids, const float* edge_ts, const float* last_update,
    const float* edge_features, const float* time_w, const float* time_b,
    const float* WeT, float* ebuf){
  __shared__ float ea_t[EE_CH][68];   // [k][edge]
  __shared__ float wls[EE_CH][64];    // [k][col]
  int tid = threadIdx.x;
  int ebase = blockIdx.x * 64;
  int ee = tid & 63, qq = tid >> 6;
  int j = ebase + ee;
  int eid = edge_ids[j];
  float rel = edge_ts[j] - last_update[eid];
  int tr = tid >> 4, tc = tid & 15;
  float4 acc[4];
  #pragma unroll
  for (int i=0;i<4;i++) acc[i] = (float4){0.f,0.f,0.f,0.f};

  for (int kc = 0; kc < 2; kc++){
    #pragma unroll 5
    for (int m = 0; m < 20; m++){
      int kk = qq*20 + m;
      int k  = kc*EE_CH + kk;
      float v = (k < TENC) ? cosf(rel*time_w[k] + time_b[k])
                           : edge_features[eid*EEMB + (k - TENC)];
      ea_t[kk][ee] = v;
    }
    #pragma unroll
    for (int it = 0; it < 5; it++){
      int idx = tid + it*256;
      int kk = idx >> 4, c4 = (idx & 15) * 4;
      *(float4*)&wls[kk][c4] = *(const float4*)&WeT[(kc*EE_CH + kk)*64 + c4];
    }
    __syncthreads();
    #pragma unroll 4
    for (int kk = 0; kk < EE_CH; kk++){
      float4 ev = *(const float4*)&ea_t[kk][tr*4];
      float4 wv = *(const float4*)&wls[kk][tc*4];
      acc[0].x += ev.x*wv.x; acc[0].y += ev.x*wv.y; acc[0].z += ev.x*wv.z; acc[0].w += ev.x*wv.w;
      acc[1].x += ev.y*wv.x; acc[1].y += ev.y*wv.y; acc[1].z += ev.y*wv.z; acc[1].w += ev.y*wv.w;
      acc[2].x += ev.z*wv.x; acc[2].y += ev.z*wv.y; acc[2].z += ev.z*wv.z; acc[2].w += ev.z*wv.w;
      acc[3].x += ev.w*wv.x; acc[3].y += ev.w*wv.y; acc[3].z += ev.w*wv.z; acc[3].w += ev.w*wv.w;
    }
    __syncthreads();
  }
  #pragma unroll
  for (int i=0;i<4;i++)
    *(float4*)&ebuf[(ebase + tr*4 + i)*OUTD + tc*4] = acc[i];
}

// ---- per-edge score -> p = exp(score); fused den: non-row-0 direct atomics,
//      row-0 per-block partial to scratch (no chain). ----
__global__ void k_score(const int* edge_index, const int* first_pos,
                        const float* qbuf, const float* kbuf, const float* ebuf,
                        float* pbuf, int* srcpos, int* tgtpos,
                        float* den, float* den0part){
  __shared__ float sden[4];
  int w = threadIdx.x >> 6;
  int j = blockIdx.x*4 + w;
  int c = threadIdx.x & 63;
  int b = j / NEDGE, e = j % NEDGE;
  int vsrc = edge_index[b*2*NEDGE + e];
  int vtgt = edge_index[b*2*NEDGE + NEDGE + e];
  int fs = first_pos[vsrc]; if (fs == 0x7FFFFFFF) fs = 0;
  int ft = first_pos[vtgt]; if (ft == 0x7FFFFFFF) ft = 0;
  float partial = qbuf[ft*OUTD + c] * (kbuf[fs*OUTD + c] + ebuf[j*OUTD + c]);
  #pragma unroll
  for (int off=32; off>0; off>>=1) partial += __shfl_down(partial, off, 64);
  if (c == 0){
    float score = partial * 0.125f;   // / sqrt(64)
    float p = expf(score);            // softmax shift-invariant; scores O(0.1)
    pbuf[j] = p;
    srcpos[j] = fs; tgtpos[j] = ft;
    sden[w] = (ft == 0) ? p : 0.f;
    if (ft != 0) atomicAdd(&den[ft], p);
  }
  __syncthreads();
  if (threadIdx.x == 0) den0part[blockIdx.x] = sden[0]+sden[1]+sden[2]+sden[3];
}

// ---- finalize den[0]: sum 4096 block partials ----
__global__ __launch_bounds__(1024) void k_fin_den(const float* den0part, float* den){
  __shared__ float part[16];
  int tid = threadIdx.x;
  float s = den0part[tid] + den0part[tid+1024] + den0part[tid+2048] + den0part[tid+3072];
  #pragma unroll
  for (int off=32; off>0; off>>=1) s += __shfl_down(s, off, 64);
  if ((tid & 63) == 0) part[tid>>6] = s;
  __syncthreads();
  if (tid == 0){
    float t = 0.f;
    #pragma unroll
    for (int i=0;i<16;i++) t += part[i];
    den[0] = t;
  }
}

// ---- weighted scatter of v_e (skip already in d_out). Edge-parallel: 16 waves/block,
//      4 edges/wave fully unrolled. Row-0 -> per-block partial row (no atomic chain). ----
__global__ __launch_bounds__(1024) void k_out(const int* srcpos, const int* tgtpos,
                                              const float* pbuf, const float* den,
                                              const float* vbuf, const float* ebuf,
                                              float* out, float* out0part){
  __shared__ float acc0[16][64];
  int tid = threadIdx.x;
  int w = tid >> 6, c = tid & 63;
  int jbase = blockIdx.x*64 + w*4;
  float a0 = 0.f;
  #pragma unroll
  for (int i=0;i<4;i++){
    int j = jbase + i;
    int ft = tgtpos[j], fs = srcpos[j];
    float alpha = pbuf[j] / den[ft];
    float val = alpha * (vbuf[fs*OUTD + c] + ebuf[j*OUTD + c]);
    if (ft == 0) a0 += val;                 // wave-uniform branch
    else atomicAdd(&out[ft*OUTD + c], val);
  }
  acc0[w][c] = a0;
  __syncthreads();
  if (w == 0){
    float t = 0.f;
    #pragma unroll
    for (int i=0;i<16;i++) t += acc0[i][c];
    out0part[blockIdx.x*64 + c] = t;
  }
}

// ---- finalize out row 0: sum 256 partial rows (single writer -> non-atomic add) ----
__global__ __launch_bounds__(1024) void k_fin_out(const float* out0part, float* out){
  __shared__ float part[16][64];
  int tid = threadIdx.x;
  int w = tid >> 6, c = tid & 63;
  float s = 0.f;
  #pragma unroll
  for (int i=0;i<16;i++) s += out0part[(w + i*16)*64 + c];
  part[w][c] = s;
  __syncthreads();
  if (w == 0){
    float t = 0.f;
    #pragma unroll
    for (int i=0;i<16;i++) t += part[i][c];
    out[c] += t;
  }
}

extern "C" void kernel_launch(void* const* d_in, const int* in_sizes, int n_in,
                              void* d_out, int out_size, void* d_ws, size_t ws_size,
                              hipStream_t stream){
  const int*   ev_type      = (const int*)  d_in[0];
  const int*   src_ids      = (const int*)  d_in[1];
  const float* src_mask     = (const float*)d_in[2];
  const int*   dst_ids      = (const int*)  d_in[3];
  const float* dst_mask     = (const float*)d_in[4];
  const int*   ev_edge      = (const int*)  d_in[5];
  const float* ev_emb       = (const float*)d_in[6];
  const float* ev_ts        = (const float*)d_in[7];
  const int*   node_ids     = (const int*)  d_in[8];
  const int*   edge_ids     = (const int*)  d_in[9];
  const int*   edge_index   = (const int*)  d_in[10];
  const float* edge_ts      = (const float*)d_in[11];
  const float* memory       = (const float*)d_in[12];
  const float* last_update  = (const float*)d_in[13];
  const float* node_feat    = (const float*)d_in[14];
  const float* edge_feat    = (const float*)d_in[15];
  const float* type_emb     = (const float*)d_in[16];
  const float* time_w       = (const float*)d_in[17];
  const float* time_b       = (const float*)d_in[18];
  const float* gru_w_ih     = (const float*)d_in[19];
  const float* gru_w_hh     = (const float*)d_in[20];
  const float* gru_b_ih     = (const float*)d_in[21];
  const float* gru_b_hh     = (const float*)d_in[22];
  const float* Wq  = (const float*)d_in[23]; const float* bq    = (const float*)d_in[24];
  const float* Wk  = (const float*)d_in[25]; const float* bk    = (const float*)d_in[26];
  const float* Wv  = (const float*)d_in[27]; const float* bv    = (const float*)d_in[28];
  const float* We  = (const float*)d_in[29];
  const float* Wsk = (const float*)d_in[30]; const float* bskip = (const float*)d_in[31];
  float* out = (float*)d_out;

  float* ws = (float*)d_ws;
  size_t off = 0;
  // --- zeroed span (accumulators) ---
  float* agg_src = ws + off; off += (size_t)MAXN*MSG;
  float* agg_dst = ws + off; off += (size_t)MAXN*MSG;
  int* cnt_src   = (int*)(ws + off); off += MAXN;
  int* cnt_dst   = (int*)(ws + off); off += MAXN;
  int* present_s = (int*)(ws + off); off += MAXN;
  int* present_d = (int*)(ws + off); off += MAXN;
  float* den     = ws + off; off += BN;
  int n_zero = (int)off;
  // --- rest (fully overwritten each call) ---
  int* first_pos = (int*)(ws + off); off += MAXN;
  float* mem_new = ws + off; off += (size_t)MAXN*MEMD;
  float* qbuf    = ws + off; off += (size_t)BN*OUTD;
  float* kbuf    = ws + off; off += (size_t)BN*OUTD;
  float* vbuf    = ws + off; off += (size_t)BN*OUTD;
  float* ebuf    = ws + off; off += (size_t)BE*OUTD;
  float* pbuf    = ws + off; off += BE;
  int* srcpos    = (int*)(ws + off); off += BE;
  int* tgtpos    = (int*)(ws + off); off += BE;
  float* den0part= ws + off; off += 4096;
  float* out0part= ws + off; off += 256*64;
  float* wihT    = ws + off; off += (size_t)MSG*192;
  float* whhT    = ws + off; off += (size_t)MEMD*192;
  float* WcatT   = ws + off; off += (size_t)INGNN*256;
  float* WeT     = ws + off; off += (size_t)EDIM*64;
  float* bcat    = ws + off; off += 256;

  k_init<<<2048, 256, 0, stream>>>(ws, n_zero, first_pos,
                                   gru_w_ih, gru_w_hh, Wq, Wk, Wv, Wsk, We,
                                   bq, bk, bv, bskip,
                                   wihT, whhT, WcatT, WeT, bcat);
  k_msg_first<<<SS + (BN + 319)/320, 320, 0, stream>>>(
      ev_type, src_ids, src_mask, dst_ids, dst_mask, ev_edge,
      ev_emb, ev_ts, memory, last_update, type_emb, time_w, time_b,
      agg_src, agg_dst, cnt_src, cnt_dst,
      node_ids, first_pos, present_s, present_d);
  k_gru<<<MAXN/NT, 192, 0, stream>>>(agg_src, agg_dst, cnt_src, cnt_dst,
                                     present_s, present_d, memory,
                                     wihT, whhT, gru_b_ih, gru_b_hh, mem_new);
  k_qkvs<<<(BN/64)*4, 256, 0, stream>>>(node_ids, node_feat, mem_new, WcatT, bcat,
                                        qbuf, kbuf, vbuf, out);
  k_edge_e<<<BE/64, 256, 0, stream>>>(edge_ids, edge_ts, last_update, edge_feat,
                                      time_w, time_b, WeT, ebuf);
  k_score<<<BE/4, 256, 0, stream>>>(edge_index, first_pos, qbuf, kbuf, ebuf,
                                    pbuf, srcpos, tgtpos, den, den0part);
  k_fin_den<<<1, 1024, 0, stream>>>(den0part, den);
  k_out<<<256, 1024, 0, stream>>>(srcpos, tgtpos, pbuf, den, vbuf, ebuf, out, out0part);
  k_fin_out<<<1, 1024, 0, stream>>>(out0part, out);
}

// Round 7
// 83.967 us; speedup vs baseline: 1.7445x; 1.1789x over previous
//
#include <hip/hip_runtime.h>
#include <math.h>

// ---- problem dims ----
#define BB 8
#define SS 512
#define NNODE 1024
#define NEDGE 2048
#define MAXN 4096
#define MAXE 8192
#define TYPED 16
#define MEMD 64
#define TENC 32
#define EEMB 128
#define OUTD 64
#define MSG 304      // 16+64+64+32+128
#define INGNN 192    // 128+64
#define EDIM 160     // 32+128
#define BN 8192      // B*N
#define BE 16384     // B*E

__device__ __forceinline__ float sigmoidf(float x){ return 1.f/(1.f + expf(-x)); }

// ---- init: zero accumulator span (float4), first_pos=INT_MAX, W transposes ----
__global__ void k_init(float* zero_base, int n_zero, int* first_pos,
                       const float* Wq, const float* Wk, const float* Wv,
                       const float* Wskip, const float* We,
                       const float* bq, const float* bk,
                       const float* bv, const float* bskip,
                       float* WcatT, float* WeT, float* bcat){
  int i = blockIdx.x*blockDim.x + threadIdx.x;
  int stride = gridDim.x*blockDim.x;
  float4* z4 = (float4*)zero_base;
  int n4 = n_zero >> 2;
  float4 zero = {0.f,0.f,0.f,0.f};
  for (int t=i; t<n4; t+=stride) z4[t] = zero;
  for (int t=i; t<MAXN; t+=stride) first_pos[t] = 0x7FFFFFFF;
  int j = i;
  if (j < 4*64*192){
    int o = j/(64*192); int rem = j%(64*192); int q=rem/192, k=rem%192;
    const float* W = (o==0)?Wq:(o==1)?Wk:(o==2)?Wv:Wskip;
    WcatT[k*256 + o*64 + q] = W[rem];
  } else {
    j -= 4*64*192;
    if (j < 64*EDIM){ int q=j/EDIM, k=j%EDIM; WeT[k*64+q] = We[j]; }
    else {
      j -= 64*EDIM;
      if (j < 256){
        const float* b = (j<64)?bq:(j<128)?bk:(j<192)?bv:bskip;
        bcat[j] = b[j&63];
      }
    }
  }
}

// ---- fused: messages for batch 0 (blocks < SS) + first-pos/presence (rest) ----
__global__ void k_msg_first(const int* ev_type, const int* src_ids, const float* src_mask,
                            const int* dst_ids, const float* dst_mask, const int* ev_edge,
                            const float* ev_emb, const float* ev_ts, const float* memory,
                            const float* last_update, const float* type_emb,
                            const float* time_w, const float* time_b,
                            float* agg_src, float* agg_dst, int* cnt_src, int* cnt_dst,
                            const int* node_ids, int* first_pos, int* ps, int* pd){
  int bb = blockIdx.x;
  if (bb < SS){
    int s = bb;
    int et = ev_type[s];
    int sid = src_ids[s], did = dst_ids[s];
    float sm = src_mask[s], dm = dst_mask[s];
    float ts = ev_ts[s];
    float ns = (et >= 3) ? 1.f : 0.f;
    float ine = (et == 3 || et == 4) ? 1.f : 0.f;
    float rel = ts - last_update[ev_edge[s]] * dm;
    float tin = ts*ine + rel*dm;
    int d = threadIdx.x;
    if (d < MSG){
      float vs, vd;
      if (d < TYPED){ float t = type_emb[et*TYPED + d]; vs = t; vd = t; }
      else if (d < 80){ int c=d-16;  vs = memory[sid*MEMD+c]*sm; vd = memory[did*MEMD+c]*dm; }
      else if (d < 144){ int c=d-80; vs = memory[did*MEMD+c]*dm; vd = memory[sid*MEMD+c]*sm; }
      else if (d < 176){ int c=d-144; float ce = cosf(tin*time_w[c]+time_b[c])*ns; vs=ce; vd=ce; }
      else { float e = ev_emb[s*EEMB + (d-176)]; vs=e; vd=e; }
      atomicAdd(&agg_src[sid*MSG+d], vs*ns);
      atomicAdd(&agg_dst[did*MSG+d], vd*dm);
    }
    if (d == MSG){ atomicAdd(&cnt_src[sid], 1); atomicAdd(&cnt_dst[did], 1); }
  } else {
    int i = (bb - SS)*320 + threadIdx.x;
    if (i < BN) atomicMin(&first_pos[node_ids[i]], i);
    if (i < BB*SS){ ps[src_ids[i]] = 1; pd[dst_ids[i]] = 1; }
  }
}

// ---- GRU memory update. NT=8 nodes/block; x staged LDS-transposed (xs_t[k][t]);
//      weights read DIRECTLY from row-major gru_w_ih/gru_w_hh as per-thread float4. ----
#define GNT 8
#define GPAD 12
__global__ __launch_bounds__(192) void k_gru(
    const float* agg_src, const float* agg_dst, const int* cnt_src, const int* cnt_dst,
    const int* ps, const int* pd, const float* memory,
    const float* w_ih, const float* w_hh, const float* b_ih, const float* b_hh,
    float* mem_new){
  __shared__ float xs_t[MSG][GPAD];
  __shared__ float hs_t[MEMD][GPAD];
  __shared__ float giL[GNT][192];
  __shared__ float ghL[GNT][192];
  __shared__ int   mode[GNT];
  __shared__ float rcnt[GNT];
  int tid = threadIdx.x;
  int base = blockIdx.x * GNT;
  if (tid < GNT){
    int n = base + tid;
    int m = pd[n] ? 2 : (ps[n] ? 1 : 0);
    mode[tid] = m;
    int c = (m==2) ? cnt_dst[n] : ((m==1) ? cnt_src[n] : 0);
    rcnt[tid] = 1.f / (float)max(c, 1);
  }
  __syncthreads();
  for (int idx = tid; idx < GNT*MSG; idx += 192){
    int t = idx / MSG, k = idx - t*MSG;
    const float* agg = (mode[t]==2) ? agg_dst : agg_src;
    xs_t[k][t] = agg[(base+t)*MSG + k] * rcnt[t];
  }
  for (int idx = tid; idx < GNT*MEMD; idx += 192){
    int t = idx / MEMD, k = idx - t*MEMD;
    hs_t[k][t] = memory[(base+t)*MEMD + k];
  }
  __syncthreads();
  // gi = x @ w_ih^T + b_ih  (thread = output col tid)
  {
    float4 a0 = {0.f,0.f,0.f,0.f}, a1 = {0.f,0.f,0.f,0.f};
    const float* wr = &w_ih[tid*MSG];
    #pragma unroll 2
    for (int k4 = 0; k4 < MSG; k4 += 4){
      float4 w4 = *(const float4*)&wr[k4];
      {
        float4 x0 = *(const float4*)&xs_t[k4][0];
        float4 x1 = *(const float4*)&xs_t[k4][4];
        a0.x += w4.x*x0.x; a0.y += w4.x*x0.y; a0.z += w4.x*x0.z; a0.w += w4.x*x0.w;
        a1.x += w4.x*x1.x; a1.y += w4.x*x1.y; a1.z += w4.x*x1.z; a1.w += w4.x*x1.w;
      }
      {
        float4 x0 = *(const float4*)&xs_t[k4+1][0];
        float4 x1 = *(const float4*)&xs_t[k4+1][4];
        a0.x += w4.y*x0.x; a0.y += w4.y*x0.y; a0.z += w4.y*x0.z; a0.w += w4.y*x0.w;
        a1.x += w4.y*x1.x; a1.y += w4.y*x1.y; a1.z += w4.y*x1.z; a1.w += w4.y*x1.w;
      }
      {
        float4 x0 = *(const float4*)&xs_t[k4+2][0];
        float4 x1 = *(const float4*)&xs_t[k4+2][4];
        a0.x += w4.z*x0.x; a0.y += w4.z*x0.y; a0.z += w4.z*x0.z; a0.w += w4.z*x0.w;
        a1.x += w4.z*x1.x; a1.y += w4.z*x1.y; a1.z += w4.z*x1.z; a1.w += w4.z*x1.w;
      }
      {
        float4 x0 = *(const float4*)&xs_t[k4+3][0];
        float4 x1 = *(const float4*)&xs_t[k4+3][4];
        a0.x += w4.w*x0.x; a0.y += w4.w*x0.y; a0.z += w4.w*x0.z; a0.w += w4.w*x0.w;
        a1.x += w4.w*x1.x; a1.y += w4.w*x1.y; a1.z += w4.w*x1.z; a1.w += w4.w*x1.w;
      }
    }
    float bi = b_ih[tid];
    giL[0][tid]=a0.x+bi; giL[1][tid]=a0.y+bi; giL[2][tid]=a0.z+bi; giL[3][tid]=a0.w+bi;
    giL[4][tid]=a1.x+bi; giL[5][tid]=a1.y+bi; giL[6][tid]=a1.z+bi; giL[7][tid]=a1.w+bi;
  }
  // gh = h @ w_hh^T + b_hh
  {
    float4 a0 = {0.f,0.f,0.f,0.f}, a1 = {0.f,0.f,0.f,0.f};
    const float* wr = &w_hh[tid*MEMD];
    #pragma unroll 2
    for (int k4 = 0; k4 < MEMD; k4 += 4){
      float4 w4 = *(const float4*)&wr[k4];
      {
        float4 x0 = *(const float4*)&hs_t[k4][0];
        float4 x1 = *(const float4*)&hs_t[k4][4];
        a0.x += w4.x*x0.x; a0.y += w4.x*x0.y; a0.z += w4.x*x0.z; a0.w += w4.x*x0.w;
        a1.x += w4.x*x1.x; a1.y += w4.x*x1.y; a1.z += w4.x*x1.z; a1.w += w4.x*x1.w;
      }
      {
        float4 x0 = *(const float4*)&hs_t[k4+1][0];
        float4 x1 = *(const float4*)&hs_t[k4+1][4];
        a0.x += w4.y*x0.x; a0.y += w4.y*x0.y; a0.z += w4.y*x0.z; a0.w += w4.y*x0.w;
        a1.x += w4.y*x1.x; a1.y += w4.y*x1.y; a1.z += w4.y*x1.z; a1.w += w4.y*x1.w;
      }
      {
        float4 x0 = *(const float4*)&hs_t[k4+2][0];
        float4 x1 = *(const float4*)&hs_t[k4+2][4];
        a0.x += w4.z*x0.x; a0.y += w4.z*x0.y; a0.z += w4.z*x0.z; a0.w += w4.z*x0.w;
        a1.x += w4.z*x1.x; a1.y += w4.z*x1.y; a1.z += w4.z*x1.z; a1.w += w4.z*x1.w;
      }
      {
        float4 x0 = *(const float4*)&hs_t[k4+3][0];
        float4 x1 = *(const float4*)&hs_t[k4+3][4];
        a0.x += w4.w*x0.x; a0.y += w4.w*x0.y; a0.z += w4.w*x0.z; a0.w += w4.w*x0.w;
        a1.x += w4.w*x1.x; a1.y += w4.w*x1.y; a1.z += w4.w*x1.z; a1.w += w4.w*x1.w;
      }
    }
    float bh = b_hh[tid];
    ghL[0][tid]=a0.x+bh; ghL[1][tid]=a0.y+bh; ghL[2][tid]=a0.z+bh; ghL[3][tid]=a0.w+bh;
    ghL[4][tid]=a1.x+bh; ghL[5][tid]=a1.y+bh; ghL[6][tid]=a1.z+bh; ghL[7][tid]=a1.w+bh;
  }
  __syncthreads();
  int cw = tid >> 6, col = tid & 63;
  for (int t = cw; t < GNT; t += 3){
    float h = hs_t[col][t];
    float outv;
    if (mode[t] == 0) outv = h;
    else {
      float r  = sigmoidf(giL[t][col]     + ghL[t][col]);
      float z  = sigmoidf(giL[t][64+col]  + ghL[t][64+col]);
      float ng = tanhf  (giL[t][128+col] + r*ghL[t][128+col]);
      outv = (1.f - z)*ng + z*h;
    }
    mem_new[(base+t)*MEMD + col] = outv;
  }
}

// ---- merged LDS-resident GEMMs: blocks [0,512) = qkvs, [512,768) = edge_e ----
#define QK_CH 96
#define EE_CH 80
__global__ __launch_bounds__(256) void k_mm(
    const int* node_ids, const float* node_feat, const float* mem_new,
    const float* WcatT, const float* bcat,
    float* qbuf, float* kbuf, float* vbuf, float* outbuf,
    const int* edge_ids, const float* edge_ts, const float* last_update,
    const float* edge_features, const float* time_w, const float* time_b,
    const float* WeT, float* ebuf){
  __shared__ float smem[QK_CH*68 + QK_CH*64];   // 12672 floats = 50.7 KB
  int tid = threadIdx.x;
  if (blockIdx.x < 512){
    float* xs_t = smem;               // [QK_CH][68]
    float* wls  = smem + QK_CH*68;    // [QK_CH][64]
    int rg = blockIdx.x >> 2, cg = blockIdx.x & 3;
    int rbase = rg * 64;
    int rr = tid & 63, qq = tid >> 6;
    int nid = node_ids[rbase + rr];
    int tr = tid >> 4, tc = tid & 15;
    float4 acc[4];
    #pragma unroll
    for (int i=0;i<4;i++) acc[i] = (float4){0.f,0.f,0.f,0.f};
    for (int kc = 0; kc < 2; kc++){
      #pragma unroll 6
      for (int m = 0; m < 24; m++){
        int kk = qq*24 + m;
        int k  = kc*QK_CH + kk;
        float v = (k < EEMB) ? node_feat[nid*EEMB + k] : mem_new[nid*MEMD + (k-EEMB)];
        xs_t[kk*68 + rr] = v;
      }
      #pragma unroll
      for (int it = 0; it < 6; it++){
        int idx = tid + it*256;
        int kk = idx >> 4, c4 = (idx & 15) * 4;
        *(float4*)&wls[kk*64 + c4] = *(const float4*)&WcatT[(kc*QK_CH + kk)*256 + cg*64 + c4];
      }
      __syncthreads();
      #pragma unroll 4
      for (int kk = 0; kk < QK_CH; kk++){
        float4 xv = *(const float4*)&xs_t[kk*68 + tr*4];
        float4 wv = *(const float4*)&wls[kk*64 + tc*4];
        acc[0].x += xv.x*wv.x; acc[0].y += xv.x*wv.y; acc[0].z += xv.x*wv.z; acc[0].w += xv.x*wv.w;
        acc[1].x += xv.y*wv.x; acc[1].y += xv.y*wv.y; acc[1].z += xv.y*wv.z; acc[1].w += xv.y*wv.w;
        acc[2].x += xv.z*wv.x; acc[2].y += xv.z*wv.y; acc[2].z += xv.z*wv.z; acc[2].w += xv.z*wv.w;
        acc[3].x += xv.w*wv.x; acc[3].y += xv.w*wv.y; acc[3].z += xv.w*wv.z; acc[3].w += xv.w*wv.w;
      }
      __syncthreads();
    }
    float4 b4 = *(const float4*)&bcat[cg*64 + tc*4];
    float* dst = (cg==0)? qbuf : (cg==1)? kbuf : (cg==2)? vbuf : outbuf;
    #pragma unroll
    for (int i=0;i<4;i++){
      float4 o = {acc[i].x+b4.x, acc[i].y+b4.y, acc[i].z+b4.z, acc[i].w+b4.w};
      *(float4*)&dst[(rbase + tr*4 + i)*OUTD + tc*4] = o;
    }
  } else {
    float* ea_t = smem;               // [EE_CH][68]
    float* wls  = smem + EE_CH*68;    // [EE_CH][64]
    int ebase = (blockIdx.x - 512) * 64;
    int ee = tid & 63, qq = tid >> 6;
    int j = ebase + ee;
    int eid = edge_ids[j];
    float rel = edge_ts[j] - last_update[eid];
    int tr = tid >> 4, tc = tid & 15;
    float4 acc[4];
    #pragma unroll
    for (int i=0;i<4;i++) acc[i] = (float4){0.f,0.f,0.f,0.f};
    for (int kc = 0; kc < 2; kc++){
      #pragma unroll 5
      for (int m = 0; m < 20; m++){
        int kk = qq*20 + m;
        int k  = kc*EE_CH + kk;
        float v = (k < TENC) ? cosf(rel*time_w[k] + time_b[k])
                             : edge_features[eid*EEMB + (k - TENC)];
        ea_t[kk*68 + ee] = v;
      }
      #pragma unroll
      for (int it = 0; it < 5; it++){
        int idx = tid + it*256;
        int kk = idx >> 4, c4 = (idx & 15) * 4;
        *(float4*)&wls[kk*64 + c4] = *(const float4*)&WeT[(kc*EE_CH + kk)*64 + c4];
      }
      __syncthreads();
      #pragma unroll 4
      for (int kk = 0; kk < EE_CH; kk++){
        float4 ev = *(const float4*)&ea_t[kk*68 + tr*4];
        float4 wv = *(const float4*)&wls[kk*64 + tc*4];
        acc[0].x += ev.x*wv.x; acc[0].y += ev.x*wv.y; acc[0].z += ev.x*wv.z; acc[0].w += ev.x*wv.w;
        acc[1].x += ev.y*wv.x; acc[1].y += ev.y*wv.y; acc[1].z += ev.y*wv.z; acc[1].w += ev.y*wv.w;
        acc[2].x += ev.z*wv.x; acc[2].y += ev.z*wv.y; acc[2].z += ev.z*wv.z; acc[2].w += ev.z*wv.w;
        acc[3].x += ev.w*wv.x; acc[3].y += ev.w*wv.y; acc[3].z += ev.w*wv.z; acc[3].w += ev.w*wv.w;
      }
      __syncthreads();
    }
    #pragma unroll
    for (int i=0;i<4;i++)
      *(float4*)&ebuf[(ebase + tr*4 + i)*OUTD + tc*4] = acc[i];
  }
}

// ---- per-edge score -> p = exp(score); den: non-row-0 direct atomics,
//      row-0 per-block partial to scratch (finalized in k_fin_out). ----
__global__ void k_score(const int* edge_index, const int* first_pos,
                        const float* qbuf, const float* kbuf, const float* ebuf,
                        float* pbuf, int* srcpos, int* tgtpos,
                        float* den, float* den0part){
  __shared__ float sden[4];
  int w = threadIdx.x >> 6;
  int j = blockIdx.x*4 + w;
  int c = threadIdx.x & 63;
  int b = j / NEDGE, e = j % NEDGE;
  int vsrc = edge_index[b*2*NEDGE + e];
  int vtgt = edge_index[b*2*NEDGE + NEDGE + e];
  int fs = first_pos[vsrc]; if (fs == 0x7FFFFFFF) fs = 0;
  int ft = first_pos[vtgt]; if (ft == 0x7FFFFFFF) ft = 0;
  float partial = qbuf[ft*OUTD + c] * (kbuf[fs*OUTD + c] + ebuf[j*OUTD + c]);
  #pragma unroll
  for (int off=32; off>0; off>>=1) partial += __shfl_down(partial, off, 64);
  if (c == 0){
    float score = partial * 0.125f;   // / sqrt(64)
    float p = expf(score);            // softmax shift-invariant; scores O(0.1)
    pbuf[j] = p;
    srcpos[j] = fs; tgtpos[j] = ft;
    sden[w] = (ft == 0) ? p : 0.f;
    if (ft != 0) atomicAdd(&den[ft], p);
  }
  __syncthreads();
  if (threadIdx.x == 0) den0part[blockIdx.x] = sden[0]+sden[1]+sden[2]+sden[3];
}

// ---- weighted scatter of v_e (skip already in d_out). Row-0 accumulates the
//      UNNORMALIZED numerator into per-block partials (no den[0] needed here). ----
__global__ __launch_bounds__(1024) void k_out(const int* srcpos, const int* tgtpos,
                                              const float* pbuf, const float* den,
                                              const float* vbuf, const float* ebuf,
                                              float* out, float* out0part){
  __shared__ float acc0[16][64];
  int tid = threadIdx.x;
  int w = tid >> 6, c = tid & 63;
  int jbase = blockIdx.x*64 + w*4;
  float a0 = 0.f;
  #pragma unroll
  for (int i=0;i<4;i++){
    int j = jbase + i;
    int ft = tgtpos[j], fs = srcpos[j];
    float p = pbuf[j];
    float ve = vbuf[fs*OUTD + c] + ebuf[j*OUTD + c];
    if (ft == 0) a0 += p * ve;              // wave-uniform branch
    else atomicAdd(&out[ft*OUTD + c], (p/den[ft]) * ve);
  }
  acc0[w][c] = a0;
  __syncthreads();
  if (w == 0){
    float t = 0.f;
    #pragma unroll
    for (int i=0;i<16;i++) t += acc0[i][c];
    out0part[blockIdx.x*64 + c] = t;
  }
}

// ---- finalize row 0: den0 = sum(den0part); out[c] += numerator0[c]/den0 ----
__global__ __launch_bounds__(1024) void k_fin_out(const float* den0part,
                                                  const float* out0part, float* out){
  __shared__ float part[16][64];
  __shared__ float dpart[16];
  __shared__ float s_inv;
  int tid = threadIdx.x;
  int w = tid >> 6, c = tid & 63;
  // den0 reduce
  float d = den0part[tid] + den0part[tid+1024] + den0part[tid+2048] + den0part[tid+3072];
  #pragma unroll
  for (int off=32; off>0; off>>=1) d += __shfl_down(d, off, 64);
  if (c == 0) dpart[w] = d;
  // row-0 numerator reduce
  float s = 0.f;
  #pragma unroll
  for (int i=0;i<16;i++) s += out0part[(w + i*16)*64 + c];
  part[w][c] = s;
  __syncthreads();
  if (tid == 0){
    float dt = 0.f;
    #pragma unroll
    for (int i=0;i<16;i++) dt += dpart[i];
    s_inv = (dt > 0.f) ? 1.f/dt : 0.f;
  }
  __syncthreads();
  if (w == 0){
    float t = 0.f;
    #pragma unroll
    for (int i=0;i<16;i++) t += part[i][c];
    out[c] += t * s_inv;
  }
}

extern "C" void kernel_launch(void* const* d_in, const int* in_sizes, int n_in,
                              void* d_out, int out_size, void* d_ws, size_t ws_size,
                              hipStream_t stream){
  const int*   ev_type      = (const int*)  d_in[0];
  const int*   src_ids      = (const int*)  d_in[1];
  const float* src_mask     = (const float*)d_in[2];
  const int*   dst_ids      = (const int*)  d_in[3];
  const float* dst_mask     = (const float*)d_in[4];
  const int*   ev_edge      = (const int*)  d_in[5];
  const float* ev_emb       = (const float*)d_in[6];
  const float* ev_ts        = (const float*)d_in[7];
  const int*   node_ids     = (const int*)  d_in[8];
  const int*   edge_ids     = (const int*)  d_in[9];
  const int*   edge_index   = (const int*)  d_in[10];
  const float* edge_ts      = (const float*)d_in[11];
  const float* memory       = (const float*)d_in[12];
  const float* last_update  = (const float*)d_in[13];
  const float* node_feat    = (const float*)d_in[14];
  const float* edge_feat    = (const float*)d_in[15];
  const float* type_emb     = (const float*)d_in[16];
  const float* time_w       = (const float*)d_in[17];
  const float* time_b       = (const float*)d_in[18];
  const float* gru_w_ih     = (const float*)d_in[19];
  const float* gru_w_hh     = (const float*)d_in[20];
  const float* gru_b_ih     = (const float*)d_in[21];
  const float* gru_b_hh     = (const float*)d_in[22];
  const float* Wq  = (const float*)d_in[23]; const float* bq    = (const float*)d_in[24];
  const float* Wk  = (const float*)d_in[25]; const float* bk    = (const float*)d_in[26];
  const float* Wv  = (const float*)d_in[27]; const float* bv    = (const float*)d_in[28];
  const float* We  = (const float*)d_in[29];
  const float* Wsk = (const float*)d_in[30]; const float* bskip = (const float*)d_in[31];
  float* out = (float*)d_out;

  float* ws = (float*)d_ws;
  size_t off = 0;
  // --- zeroed span (accumulators) ---
  float* agg_src = ws + off; off += (size_t)MAXN*MSG;
  float* agg_dst = ws + off; off += (size_t)MAXN*MSG;
  int* cnt_src   = (int*)(ws + off); off += MAXN;
  int* cnt_dst   = (int*)(ws + off); off += MAXN;
  int* present_s = (int*)(ws + off); off += MAXN;
  int* present_d = (int*)(ws + off); off += MAXN;
  float* den     = ws + off; off += BN;
  int n_zero = (int)off;
  // --- rest (fully overwritten each call) ---
  int* first_pos = (int*)(ws + off); off += MAXN;
  float* mem_new = ws + off; off += (size_t)MAXN*MEMD;
  float* qbuf    = ws + off; off += (size_t)BN*OUTD;
  float* kbuf    = ws + off; off += (size_t)BN*OUTD;
  float* vbuf    = ws + off; off += (size_t)BN*OUTD;
  float* ebuf    = ws + off; off += (size_t)BE*OUTD;
  float* pbuf    = ws + off; off += BE;
  int* srcpos    = (int*)(ws + off); off += BE;
  int* tgtpos    = (int*)(ws + off); off += BE;
  float* den0part= ws + off; off += 4096;
  float* out0part= ws + off; off += 256*64;
  float* WcatT   = ws + off; off += (size_t)INGNN*256;
  float* WeT     = ws + off; off += (size_t)EDIM*64;
  float* bcat    = ws + off; off += 256;

  k_init<<<2048, 256, 0, stream>>>(ws, n_zero, first_pos,
                                   Wq, Wk, Wv, Wsk, We, bq, bk, bv, bskip,
                                   WcatT, WeT, bcat);
  k_msg_first<<<SS + (BN + 319)/320, 320, 0, stream>>>(
      ev_type, src_ids, src_mask, dst_ids, dst_mask, ev_edge,
      ev_emb, ev_ts, memory, last_update, type_emb, time_w, time_b,
      agg_src, agg_dst, cnt_src, cnt_dst,
      node_ids, first_pos, present_s, present_d);
  k_gru<<<MAXN/GNT, 192, 0, stream>>>(agg_src, agg_dst, cnt_src, cnt_dst,
                                      present_s, present_d, memory,
                                      gru_w_ih, gru_w_hh, gru_b_ih, gru_b_hh, mem_new);
  k_mm<<<512 + BE/64, 256, 0, stream>>>(node_ids, node_feat, mem_new, WcatT, bcat,
                                        qbuf, kbuf, vbuf, out,
                                        edge_ids, edge_ts, last_update, edge_feat,
                                        time_w, time_b, WeT, ebuf);
  k_score<<<BE/4, 256, 0, stream>>>(edge_index, first_pos, qbuf, kbuf, ebuf,
                                    pbuf, srcpos, tgtpos, den, den0part);
  k_out<<<256, 1024, 0, stream>>>(srcpos, tgtpos, pbuf, den, vbuf, ebuf, out, out0part);
  k_fin_out<<<1, 1024, 0, stream>>>(den0part, out0part, out);
}